// Round 9
// baseline (248.660 us; speedup 1.0000x reference)
//
#include <hip/hip_runtime.h>
#include <hip/hip_bf16.h>
#include <math.h>

// LoRA attention, MI355X bf16-MFMA pipeline, round 9.
// 256x256x64 GEMM, 8 waves (2Mx4N), per-wave 128x64 (acc[8][4]).
// LDS 128 KiB = [2 dbuf][op][fragment-interleaved half][128x64 bf16].
// KEY (vs r6): halves are FRAGMENT-interleaved (A-slot mh = rows wm*128+mh*64+j
// for both wm), so each slot is read in exactly one phase -> 3-7 phase staging
// leads with vmcnt(6) at phases 4/8 (exact m201 ledger). 16 MFMA/barrier-pair.
// Scores fuses exp + atomic row-sum; PV = split-K2 via atomicAdd (out zeroed).

typedef __attribute__((ext_vector_type(4))) float f32x4;
typedef __attribute__((ext_vector_type(8))) short bf8;   // 8 x bf16
typedef __attribute__((ext_vector_type(4))) short bf4;   // 4 x bf16

__device__ __forceinline__ unsigned short f2bf(float f) {
  union { float f; unsigned u; } c; c.f = f;
  return (unsigned short)((c.u + 0x7fffu + ((c.u >> 16) & 1u)) >> 16);
}
__device__ __forceinline__ void gload16(const void* g, void* l) {
  __builtin_amdgcn_global_load_lds((const __attribute__((address_space(1))) void*)g,
                                   (__attribute__((address_space(3))) void*)l, 16, 0, 0);
}

// ---------------- cast fp32 -> bf16 ----------------
__global__ __launch_bounds__(256)
void k_cast(const float* __restrict__ x, __hip_bfloat16* __restrict__ o) {
  long i = ((long)blockIdx.x * 256 + threadIdx.x) * 8;
  float4 a = *(const float4*)&x[i];
  float4 b = *(const float4*)&x[i + 4];
  union { bf8 v; unsigned short h[8]; } u;
  u.h[0] = f2bf(a.x); u.h[1] = f2bf(a.y); u.h[2] = f2bf(a.z); u.h[3] = f2bf(a.w);
  u.h[4] = f2bf(b.x); u.h[5] = f2bf(b.y); u.h[6] = f2bf(b.z); u.h[7] = f2bf(b.w);
  *(bf8*)&o[i] = u.v;
}

// ---------------- Weff = W + B@A, concat [2304][768] bf16, + bias concat ----------------
__global__ __launch_bounds__(256)
void k_fold3(const float* __restrict__ W0, const float* __restrict__ A0, const float* __restrict__ B0,
             const float* __restrict__ W1, const float* __restrict__ A1, const float* __restrict__ B1,
             const float* __restrict__ W2, const float* __restrict__ A2, const float* __restrict__ B2,
             const float* __restrict__ bq, const float* __restrict__ bk, const float* __restrict__ bv,
             __hip_bfloat16* __restrict__ out, float* __restrict__ bcat) {
  int idx = blockIdx.x * 256 + threadIdx.x;
  if (idx < 2304)
    bcat[idx] = (idx < 768) ? bq[idx] : (idx < 1536) ? bk[idx - 768] : bv[idx - 1536];
  int t = idx / 589824, j = idx - t * 589824;
  const float* W = (t == 0) ? W0 : (t == 1) ? W1 : W2;
  const float* A = (t == 0) ? A0 : (t == 1) ? A1 : A2;
  const float* Bl = (t == 0) ? B0 : (t == 1) ? B1 : B2;
  int d = j % 768, o = j / 768;
  float acc = W[j];
  #pragma unroll
  for (int r = 0; r < 32; ++r) acc += Bl[o * 32 + r] * A[r * 768 + d];
  out[idx] = __float2bfloat16(acc);
}

// ---------------- 256x256x64 8-wave 8-phase GEMM ----------------
// Out[m][n] = sum_k A[m][k] * B[n][k]
// MODE 0: PV, split-K2 (z=batch*2+split): A=P'+split*2048 ld4096, B=Vt+split*2048
//         ld8192; epilogue atomicAdd(out, acc/lsum[row]) -- out must be zeroed.
// MODE 1: scores: A=Q ld1536, B=A+768; P'=exp(acc*scale) bf16 ld4096 + atomic lsum
// MODE 3: proj: col<1536 -> bf16 [8192][1536]+bias; else Vt [768][8192]+bias
template<int MODE>
__global__ __launch_bounds__(512, 2)
void k_g256(const __hip_bfloat16* __restrict__ Ag, const __hip_bfloat16* __restrict__ Bg,
            const float* __restrict__ bias, void* __restrict__ Og, void* __restrict__ Og2,
            float* __restrict__ lsum, float scale)
{
  __shared__ short lds[65536];   // 128 KiB: [dbuf2][op2][half2][128 rows x 64 k]
  constexpr int NT = (MODE == 0) ? 32 : 12;
  const int tid = threadIdx.x, w = tid >> 6, lane = tid & 63;
  const int wm = w >> 2, wn = w & 3;
  const int lnlo = lane & 15, lnhi = lane >> 4;

  // T1 XCD swizzle, N-fast tile mapping
  const int gy = gridDim.y;
  const int nwg = gridDim.x * gy;
  const int w0 = blockIdx.y * gridDim.x + blockIdx.x;
  const int wid = (w0 & 7) * (nwg >> 3) + (w0 >> 3);
  const long M0 = (long)(wid / gy) * 256;
  const long N0 = (long)(wid % gy) * 256;

  const __hip_bfloat16 *A, *B; long lda, ldb;
  int batch = blockIdx.z;
  if constexpr (MODE == 0) {
    batch = blockIdx.z >> 1;
    const int split = blockIdx.z & 1;
    A = Ag + (long)batch * 4096 * 4096 + (long)split * 2048; lda = 4096;
    B = Bg + (long)batch * 4096 + (long)split * 2048;        ldb = 8192;
  } else if constexpr (MODE == 1) {
    A = Ag + (long)batch * 4096 * 1536; B = A + 768; lda = 1536; ldb = 1536;
  } else {
    A = Ag; B = Bg; lda = 768; ldb = 768;
  }

  // --- staging: slot = fragment-interleaved half (16 KB), 2 gload16/thread ---
  // A slot mh holds rows {wm*128+mh*64+j}; slot-local row r: r<64 -> wm0, else wm1.
  // B slot nh holds rows {wn*64+nh*32+j}; slot-local r: wn=r>>5 (round0), 2+(r>>5) (round1).
  const int tr = tid >> 3;                                  // 0..63
  const int sc8 = (((tid & 7) ^ (tr & 7)) << 3);            // pre-swizzled col (elems)
  char* Lc = (char*)lds;
  auto stage = [&](int op, int h, int t) {
    const int tc = (t < NT) ? t : NT - 1;                   // clamp: benign restage
    const long koff = (long)tc * 64 + sc8;
    char* dst = Lc + (t & 1) * 65536 + op * 32768 + h * 16384 + tid * 16;
    if (op == 0) {
      gload16(A + (M0 + h * 64 + tr) * lda + koff, dst);
      gload16(A + (M0 + 128 + h * 64 + tr) * lda + koff, dst + 8192);
    } else {
      gload16(B + (N0 + (tr >> 5) * 64 + h * 32 + (tr & 31)) * ldb + koff, dst);
      gload16(B + (N0 + ((tr >> 5) + 2) * 64 + h * 32 + (tr & 31)) * ldb + koff, dst + 8192);
    }
  };
  auto rdA = [&](int mh, int mf, int k, int d) -> bf8 {     // T2-swizzled read
    const int row = wm * 64 + mf * 16 + lnlo;
    const int col = ((((k << 2) + lnhi) << 4)) ^ ((row & 7) << 4);
    return *(const bf8*)(Lc + d * 65536 + mh * 16384 + row * 128 + col);
  };
  auto rdB = [&](int nh, int nf, int k, int d) -> bf8 {
    const int row = wn * 32 + nf * 16 + lnlo;
    const int col = ((((k << 2) + lnhi) << 4)) ^ ((row & 7) << 4);
    return *(const bf8*)(Lc + d * 65536 + 32768 + nh * 16384 + row * 128 + col);
  };

  f32x4 acc[8][4] = {};
  bf8 af[4][2], bv[4][2];

#define MFMA_Q(MH, NH)                                                              \
    _Pragma("unroll")                                                               \
    for (int mf = 0; mf < 4; ++mf)                                                  \
      _Pragma("unroll")                                                             \
      for (int nf = 0; nf < 2; ++nf) {                                              \
        acc[MH*4+mf][NH*2+nf] = __builtin_amdgcn_mfma_f32_16x16x32_bf16(            \
            af[mf][0], bv[NH*2+nf][0], acc[MH*4+mf][NH*2+nf], 0, 0, 0);             \
        acc[MH*4+mf][NH*2+nf] = __builtin_amdgcn_mfma_f32_16x16x32_bf16(            \
            af[mf][1], bv[NH*2+nf][1], acc[MH*4+mf][NH*2+nf], 0, 0, 0);             \
      }

#define PH(MH, NH, RAF, RBV, SOP, SH, ST, VM) do {                                  \
    if (RAF) {                                                                      \
      _Pragma("unroll")                                                             \
      for (int mf = 0; mf < 4; ++mf)                                                \
        _Pragma("unroll")                                                           \
        for (int k = 0; k < 2; ++k) af[mf][k] = rdA(MH, mf, k, DBUF);               \
    }                                                                               \
    if (RBV) {                                                                      \
      _Pragma("unroll")                                                             \
      for (int q = 0; q < 4; ++q)                                                   \
        _Pragma("unroll")                                                           \
        for (int k = 0; k < 2; ++k) bv[q][k] = rdB(q >> 1, q & 1, k, DBUF);         \
    }                                                                               \
    stage(SOP, SH, ST);                                                             \
    asm volatile("" ::: "memory");                                                  \
    __builtin_amdgcn_s_barrier();                                                   \
    __builtin_amdgcn_s_setprio(1);                                                  \
    MFMA_Q(MH, NH)                                                                  \
    __builtin_amdgcn_s_setprio(0);                                                  \
    if (VM) asm volatile("s_waitcnt vmcnt(6)" ::: "memory");                        \
    __builtin_amdgcn_s_barrier();                                                   \
    asm volatile("" ::: "memory");                                                  \
  } while (0)

  // prologue: tile0 {A0,B0,B1,A1}, tile1 {A0,B0,B1}; vmcnt(6) retires tile0
  stage(0,0,0); stage(1,0,0); stage(1,1,0); stage(0,1,0);
  stage(0,0,1); stage(1,0,1); stage(1,1,1);
  asm volatile("s_waitcnt vmcnt(6)" ::: "memory");
  __builtin_amdgcn_s_barrier();
  asm volatile("" ::: "memory");

  for (int t = 0; t < NT; t += 2) {
    {  // tile t (buf0)
      const int DBUF = 0;
      PH(0,0, 1,1, 0,1,t+1, 0);   // read af_lo + all bv; stage A1(t+1) -> buf1
      PH(0,1, 0,0, 0,0,t+2, 0);   //                      stage A0(t+2) -> buf0
      PH(1,0, 1,0, 1,0,t+2, 0);   // read af_hi;          stage B0(t+2) -> buf0
      PH(1,1, 0,0, 1,1,t+2, 1);   //                      stage B1(t+2); vmcnt(6)
    }
    {  // tile t+1 (buf1)
      const int DBUF = 1;
      PH(0,0, 1,1, 0,1,t+2, 0);   // stage A1(t+2) -> buf0
      PH(0,1, 0,0, 0,0,t+3, 0);   // stage A0(t+3) -> buf1
      PH(1,0, 1,0, 1,0,t+3, 0);   // stage B0(t+3) -> buf1
      PH(1,1, 0,0, 1,1,t+3, 1);   // stage B1(t+3); vmcnt(6)
    }
  }
#undef PH
#undef MFMA_Q

  // epilogue: C/D map col=lane&15, row=(lane>>4)*4+r
  #pragma unroll
  for (int i = 0; i < 8; ++i) {
    const long row = M0 + wm * 128 + i * 16 + lnhi * 4;
    if constexpr (MODE == 0) {
      float* Of = (float*)Og + (long)batch * 4096 * 768;
      const float* lz = lsum + (long)batch * 4096;
      float linv[4];
      #pragma unroll
      for (int r = 0; r < 4; ++r) linv[r] = 1.0f / lz[row + r];
      #pragma unroll
      for (int j = 0; j < 4; ++j) {
        const long col = N0 + wn * 64 + j * 16 + lnlo;
        #pragma unroll
        for (int r = 0; r < 4; ++r)
          atomicAdd(&Of[(row + r) * 768 + col], acc[i][j][r] * linv[r]);
      }
    } else if constexpr (MODE == 1) {
      __hip_bfloat16* Ob = (__hip_bfloat16*)Og + (long)batch * 4096 * 4096;
      float* lz = lsum + (long)batch * 4096;
      float rs[4] = {0.f, 0.f, 0.f, 0.f};
      #pragma unroll
      for (int j = 0; j < 4; ++j) {
        const long col = N0 + wn * 64 + j * 16 + lnlo;
        #pragma unroll
        for (int r = 0; r < 4; ++r) {
          const float e = __expf(fminf(acc[i][j][r] * scale, 70.0f));
          rs[r] += e;
          *(unsigned short*)&Ob[(row + r) * 4096 + col] = f2bf(e);
        }
      }
      #pragma unroll
      for (int r = 0; r < 4; ++r) {
        float v = rs[r];
        v += __shfl_xor(v, 1); v += __shfl_xor(v, 2);
        v += __shfl_xor(v, 4); v += __shfl_xor(v, 8);
        if (lnlo == 0) atomicAdd(&lz[row + r], v);
      }
    } else {
      #pragma unroll
      for (int j = 0; j < 4; ++j) {
        const long col = N0 + wn * 64 + j * 16 + lnlo;
        const float bvl = bias[col];
        if (col < 1536) {
          __hip_bfloat16* O = (__hip_bfloat16*)Og;
          #pragma unroll
          for (int r = 0; r < 4; ++r)
            *(unsigned short*)&O[(row + r) * 1536 + col] = f2bf(acc[i][j][r] + bvl);
        } else {
          __hip_bfloat16* O2 = (__hip_bfloat16*)Og2;
          bf4 v;
          #pragma unroll
          for (int r = 0; r < 4; ++r) v[r] = (short)f2bf(acc[i][j][r] + bvl);
          *(bf4*)&O2[(col - 1536) * 8192 + row] = v;
        }
      }
    }
  }
}

extern "C" void kernel_launch(void* const* d_in, const int* in_sizes, int n_in,
                              void* d_out, int out_size, void* d_ws, size_t ws_size,
                              hipStream_t stream) {
  const float* x  = (const float*)d_in[0];
  const float* Wq = (const float*)d_in[1]; const float* bq = (const float*)d_in[2];
  const float* Wk = (const float*)d_in[3]; const float* bk = (const float*)d_in[4];
  const float* Wv = (const float*)d_in[5]; const float* bv = (const float*)d_in[6];
  const float* Aq = (const float*)d_in[7]; const float* Bq = (const float*)d_in[8];
  const float* Ak = (const float*)d_in[9]; const float* Bk = (const float*)d_in[10];
  const float* Av = (const float*)d_in[11]; const float* Bv = (const float*)d_in[12];

  // ws layout (bf16 elems), ~121 MB
  __hip_bfloat16* Xb   = (__hip_bfloat16*)d_ws;        // [8192][768]
  __hip_bfloat16* WeA  = Xb  + 6291456;                // [2304][768]
  __hip_bfloat16* QKb  = WeA + 1769472;                // [8192][1536] (Q 0-767, K 768-1535)
  __hip_bfloat16* Vt   = QKb + 12582912;               // [768][8192]
  __hip_bfloat16* Pb   = Vt  + 6291456;                // [2][4096][4096] unnormalized exp
  float*          bcat = (float*)(Pb + 33554432);      // [2304]
  float*          lsum = bcat + 2304;                  // [2][4096] row sums
  float* out = (float*)d_out;

  k_cast<<<3072, 256, 0, stream>>>(x, Xb);
  k_fold3<<<6912, 256, 0, stream>>>(Wq, Aq, Bq, Wk, Ak, Bk, Wv, Av, Bv,
                                    bq, bk, bv, WeA, bcat);
  hipMemsetAsync(lsum, 0, 8192 * sizeof(float), stream);
  hipMemsetAsync(out, 0, 2L * 4096 * 768 * sizeof(float), stream);  // PV split-K accum base

  // projections: M=8192, N=2304, K=768
  k_g256<3><<<dim3(32, 9, 1), 512, 0, stream>>>(Xb, WeA, bcat, QKb, Vt, nullptr, 1.0f);
  // scores + exp + rowsum: per batch M=N=4096, K=768
  const float sc = 0.036084391824351615f;
  k_g256<1><<<dim3(16, 16, 2), 512, 0, stream>>>(QKb, nullptr, nullptr, Pb, nullptr, lsum, sc);
  // PV: per batch M=4096, N=768, K=4096, split-K2 -> atomicAdd into zeroed out
  k_g256<0><<<dim3(16, 3, 4), 512, 0, stream>>>(Pb, Vt, nullptr, out, nullptr, lsum, 1.0f);
}

// Round 10
// 216.904 us; speedup vs baseline: 1.1464x; 1.1464x over previous
//
#include <hip/hip_runtime.h>
#include <hip/hip_bf16.h>
#include <math.h>

// LoRA attention, MI355X bf16-MFMA pipeline, round 10.
// r8 template (best known) for proj + PV. Scores replaced by an m201-faithful
// 256x256x64 8-phase kernel: raw s_barrier (NO blanket memory fences),
// lgkmcnt(8)/lgkmcnt(0) hints, vmcnt(6) w/ clobber only at phases 4/8,
// register-cached fragments (reads 12/4/8/0 per quadrant), setprio on MFMA.

typedef __attribute__((ext_vector_type(4))) float f32x4;
typedef __attribute__((ext_vector_type(8))) short bf8;   // 8 x bf16
typedef __attribute__((ext_vector_type(4))) short bf4;   // 4 x bf16

__device__ __forceinline__ unsigned short f2bf(float f) {
  union { float f; unsigned u; } c; c.f = f;
  return (unsigned short)((c.u + 0x7fffu + ((c.u >> 16) & 1u)) >> 16);
}
__device__ __forceinline__ void gload16(const void* g, void* l) {
  __builtin_amdgcn_global_load_lds((const __attribute__((address_space(1))) void*)g,
                                   (__attribute__((address_space(3))) void*)l, 16, 0, 0);
}

// ---------------- cast fp32 -> bf16 ----------------
__global__ __launch_bounds__(256)
void k_cast(const float* __restrict__ x, __hip_bfloat16* __restrict__ o) {
  long i = ((long)blockIdx.x * 256 + threadIdx.x) * 8;
  float4 a = *(const float4*)&x[i];
  float4 b = *(const float4*)&x[i + 4];
  union { bf8 v; unsigned short h[8]; } u;
  u.h[0] = f2bf(a.x); u.h[1] = f2bf(a.y); u.h[2] = f2bf(a.z); u.h[3] = f2bf(a.w);
  u.h[4] = f2bf(b.x); u.h[5] = f2bf(b.y); u.h[6] = f2bf(b.z); u.h[7] = f2bf(b.w);
  *(bf8*)&o[i] = u.v;
}

// ---------------- Weff = W + B@A, concat [2304][768] bf16, + bias concat ----------------
__global__ __launch_bounds__(256)
void k_fold3(const float* __restrict__ W0, const float* __restrict__ A0, const float* __restrict__ B0,
             const float* __restrict__ W1, const float* __restrict__ A1, const float* __restrict__ B1,
             const float* __restrict__ W2, const float* __restrict__ A2, const float* __restrict__ B2,
             const float* __restrict__ bq, const float* __restrict__ bk, const float* __restrict__ bv,
             __hip_bfloat16* __restrict__ out, float* __restrict__ bcat) {
  int idx = blockIdx.x * 256 + threadIdx.x;
  if (idx < 2304)
    bcat[idx] = (idx < 768) ? bq[idx] : (idx < 1536) ? bk[idx - 768] : bv[idx - 1536];
  int t = idx / 589824, j = idx - t * 589824;
  const float* W = (t == 0) ? W0 : (t == 1) ? W1 : W2;
  const float* A = (t == 0) ? A0 : (t == 1) ? A1 : A2;
  const float* Bl = (t == 0) ? B0 : (t == 1) ? B1 : B2;
  int d = j % 768, o = j / 768;
  float acc = W[j];
  #pragma unroll
  for (int r = 0; r < 32; ++r) acc += Bl[o * 32 + r] * A[r * 768 + d];
  out[idx] = __float2bfloat16(acc);
}

// ================= scores: 256x256x64, m201-discipline 8-phase =================
// P'[m][n] = exp(scale * sum_k Q[m][k]*K[n][k]); atomic row-sums into lsum.
// 8 waves (2Mx4N), per-wave 128x64, acc[8][4]. LDS 128 KiB:
// [dbuf2][op2][fragment-interleaved half2][128x64 bf16].
__global__ __launch_bounds__(512, 2)
void k_sc256(const __hip_bfloat16* __restrict__ QK, __hip_bfloat16* __restrict__ P,
             float* __restrict__ lsum, float scale)
{
  __shared__ short lds[65536];
  constexpr int NT = 12;
  const int tid = threadIdx.x, w = tid >> 6, lane = tid & 63;
  const int wm = w >> 2, wn = w & 3;
  const int lnlo = lane & 15, lnhi = lane >> 4;
  const long z = blockIdx.z;

  // T1 XCD swizzle, N-fast
  const int gy = gridDim.y;
  const int nwg = gridDim.x * gy;
  const int w0 = blockIdx.y * gridDim.x + blockIdx.x;
  const int wid = (w0 & 7) * (nwg >> 3) + (w0 >> 3);
  const long M0 = (long)(wid / gy) * 256;
  const long N0 = (long)(wid % gy) * 256;

  const __hip_bfloat16* A = QK + z * (4096L * 1536);   // Q
  const __hip_bfloat16* B = A + 768;                   // K
  const long ld = 1536;

  // staging (r9-verified addresses): slot = fragment-interleaved half (16 KB)
  const int tr = tid >> 3;                              // 0..63
  const int sc8 = (((tid & 7) ^ (tr & 7)) << 3);        // T2 pre-swizzled col (elems)
  char* Lc = (char*)lds;
  auto stage = [&](int op, int h, int t) {
    const int tc = (t < NT) ? t : NT - 1;               // clamp: benign restage
    const long koff = (long)tc * 64 + sc8;
    char* dst = Lc + (t & 1) * 65536 + op * 32768 + h * 16384 + tid * 16;
    if (op == 0) {
      gload16(A + (M0 + h * 64 + tr) * ld + koff, dst);
      gload16(A + (M0 + 128 + h * 64 + tr) * ld + koff, dst + 8192);
    } else {
      gload16(B + (N0 + (tr >> 5) * 64 + h * 32 + (tr & 31)) * ld + koff, dst);
      gload16(B + (N0 + ((tr >> 5) + 2) * 64 + h * 32 + (tr & 31)) * ld + koff, dst + 8192);
    }
  };
  auto rdA = [&](int mh, int mf, int k, int d) -> bf8 {  // T2-swizzled read
    const int row = wm * 64 + mf * 16 + lnlo;
    const int col = ((((k << 2) + lnhi) << 4)) ^ ((row & 7) << 4);
    return *(const bf8*)(Lc + d * 65536 + mh * 16384 + row * 128 + col);
  };
  auto rdB = [&](int nh, int nf, int k, int d) -> bf8 {
    const int row = wn * 32 + nf * 16 + lnlo;
    const int col = ((((k << 2) + lnhi) << 4)) ^ ((row & 7) << 4);
    return *(const bf8*)(Lc + d * 65536 + 32768 + nh * 16384 + row * 128 + col);
  };

  f32x4 acc[8][4] = {};
  bf8 af[4][2], bv[4][2];

#define MFMA_Q(MH, NH)                                                              \
    _Pragma("unroll")                                                               \
    for (int mf = 0; mf < 4; ++mf)                                                  \
      _Pragma("unroll")                                                             \
      for (int nf = 0; nf < 2; ++nf) {                                              \
        acc[MH*4+mf][NH*2+nf] = __builtin_amdgcn_mfma_f32_16x16x32_bf16(            \
            af[mf][0], bv[NH*2+nf][0], acc[MH*4+mf][NH*2+nf], 0, 0, 0);             \
        acc[MH*4+mf][NH*2+nf] = __builtin_amdgcn_mfma_f32_16x16x32_bf16(            \
            af[mf][1], bv[NH*2+nf][1], acc[MH*4+mf][NH*2+nf], 0, 0, 0);             \
      }

  // Phase: reads (register-cached) | stage | [lgkm8] | bar | lgkm0 | prio1 MFMA prio0 | [vmcnt6] | bar
#define PH(MH, NH, RAF, RBV, SOP, SH, ST, VM) do {                                  \
    if (RAF) {                                                                      \
      _Pragma("unroll")                                                             \
      for (int mf = 0; mf < 4; ++mf)                                                \
        _Pragma("unroll")                                                           \
        for (int k = 0; k < 2; ++k) af[mf][k] = rdA(MH, mf, k, DBUF);               \
    }                                                                               \
    if (RBV) {                                                                      \
      _Pragma("unroll")                                                             \
      for (int nf = 0; nf < 2; ++nf)                                                \
        _Pragma("unroll")                                                           \
        for (int k = 0; k < 2; ++k) bv[NH*2+nf][k] = rdB(NH, nf, k, DBUF);          \
    }                                                                               \
    stage(SOP, SH, ST);                                                             \
    if (RAF && RBV) asm volatile("s_waitcnt lgkmcnt(8)");                           \
    __builtin_amdgcn_s_barrier();                                                   \
    asm volatile("s_waitcnt lgkmcnt(0)");                                           \
    __builtin_amdgcn_s_setprio(1);                                                  \
    MFMA_Q(MH, NH)                                                                  \
    __builtin_amdgcn_s_setprio(0);                                                  \
    if (VM) asm volatile("s_waitcnt vmcnt(6)" ::: "memory");                        \
    __builtin_amdgcn_s_barrier();                                                   \
  } while (0)

  // prologue: tile0 {A0,B0,B1,A1}->buf0, tile1 {A0,B0,B1}->buf1; vmcnt(6) = tile0 landed
  stage(0,0,0); stage(1,0,0); stage(1,1,0); stage(0,1,0);
  stage(0,0,1); stage(1,0,1); stage(1,1,1);
  asm volatile("s_waitcnt vmcnt(6)" ::: "memory");
  __builtin_amdgcn_s_barrier();

  for (int t = 0; t < NT; t += 2) {
    {  // tile t (buf0): quadrants (0,0)(0,1)(1,0)(1,1); reads 12/4/8/0
      const int DBUF = 0;
      PH(0,0, 1,1, 0,1,t+1, 0);   // af0+bv0; stage A1(t+1)->buf1
      PH(0,1, 0,1, 0,0,t+2, 0);   // bv1;     stage A0(t+2)->buf0 (A0 freed P0)
      PH(1,0, 1,0, 1,0,t+2, 0);   // af1;     stage B0(t+2)->buf0 (B0 freed P0)
      PH(1,1, 0,0, 1,1,t+2, 1);   //          stage B1(t+2)->buf0 (freed P1); vmcnt(6)=tile t+1 landed
    }
    {  // tile t+1 (buf1)
      const int DBUF = 1;
      PH(0,0, 1,1, 0,1,t+2, 0);   // stage A1(t+2)->buf0 (freed tile t P2)
      PH(0,1, 0,1, 0,0,t+3, 0);   // stage A0(t+3)->buf1
      PH(1,0, 1,0, 1,0,t+3, 0);   // stage B0(t+3)->buf1
      PH(1,1, 0,0, 1,1,t+3, 1);   // stage B1(t+3)->buf1; vmcnt(6)=tile t+2 landed
    }
  }
#undef PH
#undef MFMA_Q

  // epilogue: C/D map col=lane&15, row=(lane>>4)*4+r; P'=exp, atomic row-sums
  __hip_bfloat16* Pz = P + z * (4096L * 4096);
  float* lz = lsum + z * 4096;
  #pragma unroll
  for (int i = 0; i < 8; ++i) {
    const long row = M0 + wm * 128 + i * 16 + lnhi * 4;
    float rs[4] = {0.f, 0.f, 0.f, 0.f};
    #pragma unroll
    for (int j = 0; j < 4; ++j) {
      const long col = N0 + wn * 64 + j * 16 + lnlo;
      #pragma unroll
      for (int r = 0; r < 4; ++r) {
        const float e = __expf(fminf(acc[i][j][r] * scale, 70.0f));
        rs[r] += e;
        *(unsigned short*)&Pz[(row + r) * 4096 + col] = f2bf(e);
      }
    }
    #pragma unroll
    for (int r = 0; r < 4; ++r) {
      float v = rs[r];
      v += __shfl_xor(v, 1); v += __shfl_xor(v, 2);
      v += __shfl_xor(v, 4); v += __shfl_xor(v, 8);
      if (lnlo == 0) atomicAdd(&lz[row + r], v);
    }
  }
}

// ---------------- r8 template: 128x128x64 8-wave N-marching GEMM ----------------
// MODE 0: PV (A=P' ld4096, B=Vt ld8192 +z*4096, fp32 out / lsum)  MARCH=1
// MODE 3: proj (col<1536 -> bf16 [8192][1536] +bias; else Vt +bias) MARCH=2
template<int MODE, int MARCH>
__global__ __launch_bounds__(512, 4)
void k_gm(const __hip_bfloat16* __restrict__ Ag, const __hip_bfloat16* __restrict__ Bg,
          const float* __restrict__ bias, void* __restrict__ Og, void* __restrict__ Og2,
          float* __restrict__ lsum, float scale)
{
  __shared__ short lds[32768];
  constexpr int NT = (MODE == 0) ? 64 : 12;
  constexpr int S = NT * MARCH;
  const int tid = threadIdx.x, w = tid >> 6, lane = tid & 63;
  const int wm = w >> 2, wn = w & 3;
  const int lnlo = lane & 15, lnhi = lane >> 4;

  const int gy = gridDim.y;
  const int nwg = gridDim.x * gy;
  const int w0 = blockIdx.y * gridDim.x + blockIdx.x;
  const int wid = (w0 & 7) * (nwg >> 3) + (w0 >> 3);
  const long M0 = (long)(wid / gy) * 128;
  const long NG0 = (long)(wid % gy) * (128 * MARCH);

  const __hip_bfloat16 *A, *B; long lda, ldb;
  if constexpr (MODE == 0) {
    A = Ag + (long)blockIdx.z * 4096 * 4096; lda = 4096;
    B = Bg + (long)blockIdx.z * 4096;        ldb = 8192;
  } else {
    A = Ag; B = Bg; lda = 768; ldb = 768;
  }

  const int srow = tid >> 3;
  const int scol = (((tid & 7) ^ (srow & 7)) << 3);
  const __hip_bfloat16* pA[2] = { A + (M0 + srow) * lda + scol, A + (M0 + 64 + srow) * lda + scol };
  const __hip_bfloat16* pB[2] = { B + (NG0 + srow) * ldb + scol, B + (NG0 + 64 + srow) * ldb + scol };
  char* Lc = (char*)lds;
  const int wbyte = w * 1024;
  auto stage = [&](int op, int h, int s) {
    char* dst = Lc + (s & 1) * 32768 + op * 16384 + h * 8192 + wbyte;
    long off;
    if (op == 0) off = (long)(s % NT) * 64;
    else         off = (long)(s / NT) * 128 * ldb + (long)(s % NT) * 64;
    gload16((op ? pB[h] : pA[h]) + off, dst);
  };
  auto rdA = [&](int row, int k, int d) -> bf8 {
    const int sb = ((k << 6) + (lnhi << 4)) ^ ((row & 7) << 4);
    return *(const bf8*)(Lc + d * 32768 + row * 128 + sb);
  };
  auto rdB = [&](int row, int k, int d) -> bf8 {
    const int sb = ((k << 6) + (lnhi << 4)) ^ ((row & 7) << 4);
    return *(const bf8*)(Lc + d * 32768 + 16384 + row * 128 + sb);
  };

  f32x4 acc[4][2] = {};

  auto dump = [&](int j) {
    #pragma unroll
    for (int mi = 0; mi < 4; ++mi) {
      const long row = M0 + wm * 64 + mi * 16 + lnhi * 4;
      if constexpr (MODE == 0) {
        float* Of = (float*)Og + (long)blockIdx.z * 4096 * 768;
        const float* lz = lsum + (long)blockIdx.z * 4096;
        float linv[4];
        #pragma unroll
        for (int r = 0; r < 4; ++r) linv[r] = 1.0f / lz[row + r];
        #pragma unroll
        for (int ni = 0; ni < 2; ++ni) {
          const long col = NG0 + wn * 32 + ni * 16 + lnlo;
          #pragma unroll
          for (int r = 0; r < 4; ++r) Of[(row + r) * 768 + col] = acc[mi][ni][r] * linv[r];
        }
      } else {
        #pragma unroll
        for (int ni = 0; ni < 2; ++ni) {
          const long col = NG0 + (long)j * 128 + wn * 32 + ni * 16 + lnlo;
          const float bvl = bias[col];
          if (col < 1536) {
            __hip_bfloat16* O = (__hip_bfloat16*)Og;
            #pragma unroll
            for (int r = 0; r < 4; ++r)
              *(unsigned short*)&O[(row + r) * 1536 + col] = f2bf(acc[mi][ni][r] + bvl);
          } else {
            __hip_bfloat16* O2 = (__hip_bfloat16*)Og2;
            bf4 v;
            #pragma unroll
            for (int r = 0; r < 4; ++r) v[r] = (short)f2bf(acc[mi][ni][r] + bvl);
            *(bf4*)&O2[(col - 1536) * 8192 + row] = v;
          }
        }
      }
    }
    #pragma unroll
    for (int mi = 0; mi < 4; ++mi)
      #pragma unroll
      for (int ni = 0; ni < 2; ++ni) acc[mi][ni] = (f32x4){0.f, 0.f, 0.f, 0.f};
  };

  stage(1,0,0); stage(1,1,0); stage(0,0,0); stage(0,1,0);
  stage(1,0,1); stage(1,1,1);
  asm volatile("s_waitcnt vmcnt(2)" ::: "memory");
  __builtin_amdgcn_s_barrier();
  asm volatile("" ::: "memory");

  bf8 af[2][2], bv[2][2];
  for (int s = 0; s < S; s += 2) {
    if (MARCH > 1 && s > 0 && (s % NT) == 0) dump(s / NT - 1);
    const int s1 = s + 1;
    const int s2 = (s + 2 < S) ? s + 2 : S - 1;
    const int s3 = (s + 3 < S) ? s + 3 : S - 1;

    #pragma unroll
    for (int m = 0; m < 2; ++m)
      #pragma unroll
      for (int k = 0; k < 2; ++k) af[m][k] = rdA(wm * 64 + m * 16 + lnlo, k, 0);
    #pragma unroll
    for (int n = 0; n < 2; ++n)
      #pragma unroll
      for (int k = 0; k < 2; ++k) bv[n][k] = rdB(wn * 32 + n * 16 + lnlo, k, 0);
    stage(0,0,s1); stage(0,1,s1);
    asm volatile("" ::: "memory");
    __builtin_amdgcn_s_barrier();
    __builtin_amdgcn_s_setprio(1);
    #pragma unroll
    for (int m = 0; m < 2; ++m)
      #pragma unroll
      for (int n = 0; n < 2; ++n) {
        acc[m][n] = __builtin_amdgcn_mfma_f32_16x16x32_bf16(af[m][0], bv[n][0], acc[m][n], 0,0,0);
        acc[m][n] = __builtin_amdgcn_mfma_f32_16x16x32_bf16(af[m][1], bv[n][1], acc[m][n], 0,0,0);
      }
    __builtin_amdgcn_s_setprio(0);
    __builtin_amdgcn_s_barrier();
    asm volatile("" ::: "memory");

    #pragma unroll
    for (int m = 0; m < 2; ++m)
      #pragma unroll
      for (int k = 0; k < 2; ++k) af[m][k] = rdA(wm * 64 + 32 + m * 16 + lnlo, k, 0);
    stage(1,0,s2); stage(1,1,s2);
    asm volatile("" ::: "memory");
    __builtin_amdgcn_s_barrier();
    __builtin_amdgcn_s_setprio(1);
    #pragma unroll
    for (int m = 0; m < 2; ++m)
      #pragma unroll
      for (int n = 0; n < 2; ++n) {
        acc[2+m][n] = __builtin_amdgcn_mfma_f32_16x16x32_bf16(af[m][0], bv[n][0], acc[2+m][n], 0,0,0);
        acc[2+m][n] = __builtin_amdgcn_mfma_f32_16x16x32_bf16(af[m][1], bv[n][1], acc[2+m][n], 0,0,0);
      }
    __builtin_amdgcn_s_setprio(0);
    asm volatile("s_waitcnt vmcnt(2)" ::: "memory");
    __builtin_amdgcn_s_barrier();
    asm volatile("" ::: "memory");

    #pragma unroll
    for (int m = 0; m < 2; ++m)
      #pragma unroll
      for (int k = 0; k < 2; ++k) af[m][k] = rdA(wm * 64 + m * 16 + lnlo, k, 1);
    #pragma unroll
    for (int n = 0; n < 2; ++n)
      #pragma unroll
      for (int k = 0; k < 2; ++k) bv[n][k] = rdB(wn * 32 + n * 16 + lnlo, k, 1);
    stage(0,0,s2); stage(0,1,s2);
    asm volatile("" ::: "memory");
    __builtin_amdgcn_s_barrier();
    __builtin_amdgcn_s_setprio(1);
    #pragma unroll
    for (int m = 0; m < 2; ++m)
      #pragma unroll
      for (int n = 0; n < 2; ++n) {
        acc[m][n] = __builtin_amdgcn_mfma_f32_16x16x32_bf16(af[m][0], bv[n][0], acc[m][n], 0,0,0);
        acc[m][n] = __builtin_amdgcn_mfma_f32_16x16x32_bf16(af[m][1], bv[n][1], acc[m][n], 0,0,0);
      }
    __builtin_amdgcn_s_setprio(0);
    __builtin_amdgcn_s_barrier();
    asm volatile("" ::: "memory");

    #pragma unroll
    for (int m = 0; m < 2; ++m)
      #pragma unroll
      for (int k = 0; k < 2; ++k) af[m][k] = rdA(wm * 64 + 32 + m * 16 + lnlo, k, 1);
    stage(1,0,s3); stage(1,1,s3);
    asm volatile("" ::: "memory");
    __builtin_amdgcn_s_barrier();
    __builtin_amdgcn_s_setprio(1);
    #pragma unroll
    for (int m = 0; m < 2; ++m)
      #pragma unroll
      for (int n = 0; n < 2; ++n) {
        acc[2+m][n] = __builtin_amdgcn_mfma_f32_16x16x32_bf16(af[m][0], bv[n][0], acc[2+m][n], 0,0,0);
        acc[2+m][n] = __builtin_amdgcn_mfma_f32_16x16x32_bf16(af[m][1], bv[n][1], acc[2+m][n], 0,0,0);
      }
    __builtin_amdgcn_s_setprio(0);
    asm volatile("s_waitcnt vmcnt(2)" ::: "memory");
    __builtin_amdgcn_s_barrier();
    asm volatile("" ::: "memory");
  }

  dump(MARCH - 1);
}

extern "C" void kernel_launch(void* const* d_in, const int* in_sizes, int n_in,
                              void* d_out, int out_size, void* d_ws, size_t ws_size,
                              hipStream_t stream) {
  const float* x  = (const float*)d_in[0];
  const float* Wq = (const float*)d_in[1]; const float* bq = (const float*)d_in[2];
  const float* Wk = (const float*)d_in[3]; const float* bk = (const float*)d_in[4];
  const float* Wv = (const float*)d_in[5]; const float* bv = (const float*)d_in[6];
  const float* Aq = (const float*)d_in[7]; const float* Bq = (const float*)d_in[8];
  const float* Ak = (const float*)d_in[9]; const float* Bk = (const float*)d_in[10];
  const float* Av = (const float*)d_in[11]; const float* Bv = (const float*)d_in[12];

  // ws layout (bf16 elems), ~121 MB
  __hip_bfloat16* Xb   = (__hip_bfloat16*)d_ws;        // [8192][768]
  __hip_bfloat16* WeA  = Xb  + 6291456;                // [2304][768]
  __hip_bfloat16* QKb  = WeA + 1769472;                // [8192][1536] (Q 0-767, K 768-1535)
  __hip_bfloat16* Vt   = QKb + 12582912;               // [768][8192]
  __hip_bfloat16* Pb   = Vt  + 6291456;                // [2][4096][4096] unnormalized exp
  float*          bcat = (float*)(Pb + 33554432);      // [2304]
  float*          lsum = bcat + 2304;                  // [2][4096] row sums
  float* out = (float*)d_out;

  k_cast<<<3072, 256, 0, stream>>>(x, Xb);
  k_fold3<<<6912, 256, 0, stream>>>(Wq, Aq, Bq, Wk, Ak, Bk, Wv, Av, Bv,
                                    bq, bk, bv, WeA, bcat);
  hipMemsetAsync(lsum, 0, 8192 * sizeof(float), stream);

  // projections: M=8192, N=2304, K=768 (r8 template, march 2)
  k_gm<3, 2><<<dim3(64, 9, 1), 512, 0, stream>>>(Xb, WeA, bcat, QKb, Vt, nullptr, 1.0f);
  // scores + exp + rowsum: per batch M=N=4096, K=768 (m201-discipline 256^2)
  const float sc = 0.036084391824351615f;
  k_sc256<<<dim3(16, 16, 2), 512, 0, stream>>>(QKb, Pb, lsum, sc);
  // PV: per batch M=4096, N=768, K=4096 (r8 template, march 1)
  k_gm<0, 1><<<dim3(32, 6, 2), 512, 0, stream>>>(Pb, Vt, nullptr, out, nullptr, lsum, 1.0f);
}